// Round 6
// baseline (890.638 us; speedup 1.0000x reference)
//
#include <hip/hip_runtime.h>
#include <hip/hip_cooperative_groups.h>

namespace cg = cooperative_groups;

#define N_PTS 16384
#define NH 16
#define NC 192
#define NK 43
#define ND 2
#define BN_EPS 1e-5f

typedef __attribute__((ext_vector_type(8))) short bf16x8;
typedef __attribute__((ext_vector_type(4))) float f32x4;

static __device__ __forceinline__ short f2bf(float f) {
    union { float f; unsigned u; } x; x.f = f;
    unsigned r = x.u + (0x7fffu + ((x.u >> 16) & 1u));   // RNE
    return (short)(r >> 16);
}
static __device__ __forceinline__ float bf2f(short s) {
    union { unsigned u; float f; } x; x.u = ((unsigned)(unsigned short)s) << 16;
    return x.f;
}

// ONE cooperative kernel, phases separated by grid.sync():
//  P0 weight shuffle -> B-frag layout
//  per layer d: P1 gemm1 (d=1: fused bn3+skip+relu, stores X1) -> T + per-wave BN partials
//               P2 BN1 finalize | P3 kpconv (bn1 inline on gather, BN2 partials)
//               P4 BN2 finalize | P5 gemm3 (bn2 inline on A)  -> T2 + partials
//               P6 BN3 finalize
//  P7 out = relu(X1 + bn3(T2))
__global__ __launch_bounds__(256, 2) void k_mega(
    const float* __restrict__ coord, const float* __restrict__ feat,
    const int* __restrict__ ridx, const float* __restrict__ kp,
    const float* __restrict__ W1, const float* __restrict__ Wk,
    const float* __restrict__ W3,
    const float* __restrict__ g1, const float* __restrict__ b1,
    const float* __restrict__ g2, const float* __restrict__ b2,
    const float* __restrict__ g3, const float* __restrict__ b3,
    float* __restrict__ out,
    short* __restrict__ Wb, short* __restrict__ T, short* __restrict__ U,
    short* __restrict__ T2, float* __restrict__ X1,
    float* __restrict__ part, float* __restrict__ stats)
{
    cg::grid_group grid = cg::this_grid();
    __shared__ __align__(16) short wk_s[12288];     // Wk B-frags, 24 KiB
    __shared__ __align__(16) float kp_s[64][4];

    const int tid  = threadIdx.x;
    const int wave = tid >> 6, lane = tid & 63;
    const int quad = lane >> 4, cl = lane & 15;
    const int nw = gridDim.x * 4;
    const int gw = blockIdx.x * 4 + wave;

    // ---- P0: shuffle all weights into MFMA B-frag-ready bf16 layout ----
    for (int t = gw; t < 336; t += nw) {
        int dd = t / 168, r = t % 168;
        const float* src; short* dst; int kb, Ks, tile;
        if (r < 72)      { src = W1 + dd*NC*NC; dst = Wb + dd*86016;         kb = 6; Ks = NC; tile = r; }
        else if (r < 96) { src = Wk + dd*NK*NC; dst = Wb + dd*86016 + 36864; kb = 2; Ks = NK; tile = r - 72; }
        else             { src = W3 + dd*NC*NC; dst = Wb + dd*86016 + 49152; kb = 6; Ks = NC; tile = r - 96; }
        int nt = tile / kb, ks = tile % kb;
        bf16x8 vv;
#pragma unroll
        for (int j = 0; j < 8; ++j) {
            int k = ks*32 + quad*8 + j;
            vv[j] = (k < Ks) ? f2bf(src[k*NC + nt*16 + cl]) : (short)0;
        }
        *(bf16x8*)(dst + ((nt*kb + ks)*64 + lane)*8) = vv;
    }
    grid.sync();

    // per-channel stat finalize helper: a = g*rsqrt(var+eps), s = b - m*a
    auto stat_phase = [&](int nb, const float* g, const float* b, float* st) {
        for (int c = gw; c < 192; c += nw) {
            float s = 0.f, sq = 0.f;
            for (int i = lane; i < nb; i += 64) {
                s  += part[i*384 + c];
                sq += part[i*384 + 192 + c];
            }
#pragma unroll
            for (int o = 1; o < 64; o <<= 1) { s += __shfl_xor(s, o); sq += __shfl_xor(sq, o); }
            if (lane == 0) {
                float m = s * (1.f / N_PTS);
                float var = sq * (1.f / N_PTS) - m * m;
                float a = rsqrtf(var + BN_EPS) * g[c];
                st[c] = a;
                st[192 + c] = b[c] - m * a;
            }
        }
    };

    for (int d = 0; d < ND; ++d) {
        const short* W1b = Wb + d*86016;
        const short* Wkb = W1b + 36864;
        const short* W3b = W1b + 49152;
        float* st1 = stats + (d*3 + 0)*384;
        float* st2 = stats + (d*3 + 1)*384;
        float* st3 = stats + (d*3 + 2)*384;
        const float* st3p = stats + 2*384;   // layer 0's bn3 (used when d==1)

        // ---- P1: gemm1 -> T, part[0..1024) ----
        for (int tile = gw; tile < 1024; tile += nw) {
            const int row = tile*16 + cl;
            f32x4 acc[12];
#pragma unroll
            for (int nt = 0; nt < 12; ++nt) acc[nt] = (f32x4){0.f, 0.f, 0.f, 0.f};
#pragma unroll
            for (int ks = 0; ks < 6; ++ks) {
                const int k0 = ks*32 + quad*8;
                const float* ap = feat + row*NC + k0;
                float4 a0 = *(const float4*)ap;
                float4 a1v = *(const float4*)(ap + 4);
                float x[8] = {a0.x, a0.y, a0.z, a0.w, a1v.x, a1v.y, a1v.z, a1v.w};
                if (d == 1) {   // fused: x = relu(feat + bn3_L0(T2)); store X1
                    bf16x8 t2 = *(const bf16x8*)(T2 + row*NC + k0);
                    float4 pa0 = *(const float4*)(st3p + k0), pa1 = *(const float4*)(st3p + k0 + 4);
                    float4 ps0 = *(const float4*)(st3p + 192 + k0), ps1 = *(const float4*)(st3p + 192 + k0 + 4);
                    float pav[8] = {pa0.x, pa0.y, pa0.z, pa0.w, pa1.x, pa1.y, pa1.z, pa1.w};
                    float psv[8] = {ps0.x, ps0.y, ps0.z, ps0.w, ps1.x, ps1.y, ps1.z, ps1.w};
#pragma unroll
                    for (int j = 0; j < 8; ++j)
                        x[j] = fmaxf(x[j] + fmaf(pav[j], bf2f(t2[j]), psv[j]), 0.f);
                    *(float4*)(X1 + row*NC + k0)     = (float4){x[0], x[1], x[2], x[3]};
                    *(float4*)(X1 + row*NC + k0 + 4) = (float4){x[4], x[5], x[6], x[7]};
                }
                bf16x8 af;
#pragma unroll
                for (int j = 0; j < 8; ++j) af[j] = f2bf(x[j]);
#pragma unroll
                for (int nt = 0; nt < 12; ++nt) {
                    bf16x8 bf = *(const bf16x8*)(W1b + ((nt*6 + ks)*64 + lane)*8);
                    acc[nt] = __builtin_amdgcn_mfma_f32_16x16x32_bf16(af, bf, acc[nt], 0, 0, 0);
                }
            }
#pragma unroll
            for (int nt = 0; nt < 12; ++nt) {
                int c = nt*16 + cl;
                float s = 0.f, sq = 0.f;
#pragma unroll
                for (int r = 0; r < 4; ++r) {
                    float v = acc[nt][r];
                    T[(tile*16 + quad*4 + r)*NC + c] = f2bf(v);
                    s += v; sq = fmaf(v, v, sq);
                }
                s += __shfl_xor(s, 16); s += __shfl_xor(s, 32);
                sq += __shfl_xor(sq, 16); sq += __shfl_xor(sq, 32);
                if (quad == 0) { part[tile*384 + c] = s; part[tile*384 + 192 + c] = sq; }
            }
        }
        grid.sync();

        // ---- P2: BN1 finalize ----
        stat_phase(1024, g1 + d*NC, b1 + d*NC, st1);
        grid.sync();

        // ---- P3: kpconv (bn1 inline), 8 points per wave, BN2 partials ----
        {
            const float4* src = (const float4*)Wkb;
            float4* dst = (float4*)wk_s;
            for (int j = tid; j < 1536; j += 256) dst[j] = src[j];
            if (tid < 64) {
                bool ok = tid < NK;
                kp_s[tid][0] = ok ? kp[tid*3 + 0] : 0.f;
                kp_s[tid][1] = ok ? kp[tid*3 + 1] : 0.f;
                kp_s[tid][2] = ok ? kp[tid*3 + 2] : 0.f;
            }
        }
        __syncthreads();
        float a1r[12], s1r[12];
#pragma unroll
        for (int nt = 0; nt < 12; ++nt) {
            a1r[nt] = st1[nt*16 + cl];
            s1r[nt] = st1[192 + nt*16 + cl];
        }
        const unsigned short* Tu = (const unsigned short*)T;
        for (int pg = gw; pg < 2048; pg += nw) {
            float su[12], squ[12];
#pragma unroll
            for (int nt = 0; nt < 12; ++nt) { su[nt] = 0.f; squ[nt] = 0.f; }
            for (int pp = 0; pp < 8; ++pp) {
                const int n = pg*8 + pp;
                int idh = 0; float nbx = 0.f, nby = 0.f, nbz = 0.f;
                if (lane < NH) {
                    idh = ridx[n*NH + lane];
                    nbx = coord[idh*3 + 0] - coord[n*3 + 0];
                    nby = coord[idh*3 + 1] - coord[n*3 + 1];
                    nbz = coord[idh*3 + 2] - coord[n*3 + 2];
                }
                const float nx = __shfl(nbx, cl), ny = __shfl(nby, cl), nz = __shfl(nbz, cl);
                int rowb[4];
#pragma unroll
                for (int r = 0; r < 4; ++r) rowb[r] = __shfl(idh, quad*4 + r) * NC;

                // hoisted gather (48 loads) ahead of influence+MFMA
                unsigned short xv[12][4];
#pragma unroll
                for (int nt = 0; nt < 12; ++nt)
#pragma unroll
                    for (int r = 0; r < 4; ++r)
                        xv[nt][r] = Tu[rowb[r] + nt*16 + cl];

                bf16x8 af[2];
#pragma unroll
                for (int ks = 0; ks < 2; ++ks) {
#pragma unroll
                    for (int j = 0; j < 8; ++j) {
                        int k = ks*32 + quad*8 + j;
                        float dx = nx - kp_s[k][0];
                        float dy = ny - kp_s[k][1];
                        float dz = nz - kp_s[k][2];
                        float dist = sqrtf(fmaf(dx, dx, fmaf(dy, dy, dz*dz)));
                        float w = fmaxf(1.f - dist, 0.f);   // SIGMA = 1
                        if (k >= NK) w = 0.f;
                        af[ks][j] = f2bf(w);
                    }
                }
                f32x4 acc[12];
#pragma unroll
                for (int nt = 0; nt < 12; ++nt) {
                    bf16x8 b0 = *(const bf16x8*)(wk_s + ((nt*2 + 0)*64 + lane)*8);
                    bf16x8 b1v = *(const bf16x8*)(wk_s + ((nt*2 + 1)*64 + lane)*8);
                    f32x4 z = (f32x4){0.f, 0.f, 0.f, 0.f};
                    z = __builtin_amdgcn_mfma_f32_16x16x32_bf16(af[0], b0, z, 0, 0, 0);
                    acc[nt] = __builtin_amdgcn_mfma_f32_16x16x32_bf16(af[1], b1v, z, 0, 0, 0);
                }
#pragma unroll
                for (int nt = 0; nt < 12; ++nt) {
                    float u = 0.f;
#pragma unroll
                    for (int r = 0; r < 4; ++r) {
                        float t = bf2f((short)xv[nt][r]);
                        float xr = fmaxf(fmaf(a1r[nt], t, s1r[nt]), 0.f);   // bn1+relu inline
                        u = fmaf(acc[nt][r], xr, u);
                    }
                    u += __shfl_xor(u, 16);
                    u += __shfl_xor(u, 32);
                    if (quad == 0) U[n*NC + nt*16 + cl] = f2bf(u);
                    su[nt] += u; squ[nt] = fmaf(u, u, squ[nt]);
                }
            }
            if (quad == 0) {
#pragma unroll
                for (int nt = 0; nt < 12; ++nt) {
                    part[pg*384 + nt*16 + cl] = su[nt];
                    part[pg*384 + 192 + nt*16 + cl] = squ[nt];
                }
            }
        }
        grid.sync();

        // ---- P4: BN2 finalize ----
        stat_phase(2048, g2 + d*NC, b2 + d*NC, st2);
        grid.sync();

        // ---- P5: gemm3 (bn2 inline on A) -> T2, part[0..1024) ----
        for (int tile = gw; tile < 1024; tile += nw) {
            const int row = tile*16 + cl;
            f32x4 acc[12];
#pragma unroll
            for (int nt = 0; nt < 12; ++nt) acc[nt] = (f32x4){0.f, 0.f, 0.f, 0.f};
#pragma unroll
            for (int ks = 0; ks < 6; ++ks) {
                const int k0 = ks*32 + quad*8;
                bf16x8 u8 = *(const bf16x8*)(U + row*NC + k0);
                float4 aa0 = *(const float4*)(st2 + k0), aa1 = *(const float4*)(st2 + k0 + 4);
                float4 ss0 = *(const float4*)(st2 + 192 + k0), ss1 = *(const float4*)(st2 + 192 + k0 + 4);
                float av[8] = {aa0.x, aa0.y, aa0.z, aa0.w, aa1.x, aa1.y, aa1.z, aa1.w};
                float sv[8] = {ss0.x, ss0.y, ss0.z, ss0.w, ss1.x, ss1.y, ss1.z, ss1.w};
                bf16x8 af;
#pragma unroll
                for (int j = 0; j < 8; ++j)
                    af[j] = f2bf(fmaxf(fmaf(av[j], bf2f(u8[j]), sv[j]), 0.f));
#pragma unroll
                for (int nt = 0; nt < 12; ++nt) {
                    bf16x8 bf = *(const bf16x8*)(W3b + ((nt*6 + ks)*64 + lane)*8);
                    acc[nt] = __builtin_amdgcn_mfma_f32_16x16x32_bf16(af, bf, acc[nt], 0, 0, 0);
                }
            }
#pragma unroll
            for (int nt = 0; nt < 12; ++nt) {
                int c = nt*16 + cl;
                float s = 0.f, sq = 0.f;
#pragma unroll
                for (int r = 0; r < 4; ++r) {
                    float v = acc[nt][r];
                    T2[(tile*16 + quad*4 + r)*NC + c] = f2bf(v);
                    s += v; sq = fmaf(v, v, sq);
                }
                s += __shfl_xor(s, 16); s += __shfl_xor(s, 32);
                sq += __shfl_xor(sq, 16); sq += __shfl_xor(sq, 32);
                if (quad == 0) { part[tile*384 + c] = s; part[tile*384 + 192 + c] = sq; }
            }
        }
        grid.sync();

        // ---- P6: BN3 finalize ----
        stat_phase(1024, g3 + d*NC, b3 + d*NC, st3);
        grid.sync();
    }

    // ---- P7: out = relu(X1 + bn3_L1(T2)) ----
    {
        const float* st3 = stats + 5*384;
        const int tg = blockIdx.x*256 + tid, tstride = gridDim.x*256;
        for (int i = tg; i < N_PTS*NC/8; i += tstride) {
            int c0 = (i*8) % 192;
            bf16x8 t2 = *(const bf16x8*)(T2 + (long)i*8);
            float4 x0 = *(const float4*)(X1 + (long)i*8);
            float4 x1 = *(const float4*)(X1 + (long)i*8 + 4);
            float4 aa0 = *(const float4*)(st3 + c0), aa1 = *(const float4*)(st3 + c0 + 4);
            float4 ss0 = *(const float4*)(st3 + 192 + c0), ss1 = *(const float4*)(st3 + 192 + c0 + 4);
            float4 o0, o1;
            o0.x = fmaxf(x0.x + fmaf(aa0.x, bf2f(t2[0]), ss0.x), 0.f);
            o0.y = fmaxf(x0.y + fmaf(aa0.y, bf2f(t2[1]), ss0.y), 0.f);
            o0.z = fmaxf(x0.z + fmaf(aa0.z, bf2f(t2[2]), ss0.z), 0.f);
            o0.w = fmaxf(x0.w + fmaf(aa0.w, bf2f(t2[3]), ss0.w), 0.f);
            o1.x = fmaxf(x1.x + fmaf(aa1.x, bf2f(t2[4]), ss1.x), 0.f);
            o1.y = fmaxf(x1.y + fmaf(aa1.y, bf2f(t2[5]), ss1.y), 0.f);
            o1.z = fmaxf(x1.z + fmaf(aa1.z, bf2f(t2[6]), ss1.z), 0.f);
            o1.w = fmaxf(x1.w + fmaf(aa1.w, bf2f(t2[7]), ss1.w), 0.f);
            *(float4*)(out + (long)i*8)     = o0;
            *(float4*)(out + (long)i*8 + 4) = o1;
        }
    }
}

extern "C" void kernel_launch(void* const* d_in, const int* in_sizes, int n_in,
                              void* d_out, int out_size, void* d_ws, size_t ws_size,
                              hipStream_t stream) {
    const float* coord = (const float*)d_in[0];
    const float* feat  = (const float*)d_in[1];
    const int*   ridx  = (const int*)d_in[2];
    const float* kp    = (const float*)d_in[3];
    const float* W1    = (const float*)d_in[4];
    const float* Wk    = (const float*)d_in[5];
    const float* W3    = (const float*)d_in[6];
    const float* g1    = (const float*)d_in[7];
    const float* b1    = (const float*)d_in[8];
    const float* g2    = (const float*)d_in[9];
    const float* b2    = (const float*)d_in[10];
    const float* g3    = (const float*)d_in[11];
    const float* b3    = (const float*)d_in[12];
    float* out = (float*)d_out;

    // ws (floats): X1 | part[2048*384] | stats[2304] | then shorts: T | U | T2 | Wb   ~= 35 MB
    float* X1    = (float*)d_ws;
    float* part  = X1 + N_PTS * NC;
    float* stats = part + 2048 * 384;
    short* T  = (short*)(stats + 2304);
    short* U  = T + N_PTS * NC;
    short* T2 = U + N_PTS * NC;
    short* Wb = T2 + N_PTS * NC;

    int nbpc = 2;
    hipOccupancyMaxActiveBlocksPerMultiprocessor(&nbpc, k_mega, 256, 0);
    if (nbpc < 1) nbpc = 1;
    long grid = (long)nbpc * 256;          // 256 CUs on MI355X
    if (grid > 512) grid = 512;

    void* args[] = {
        (void*)&coord, (void*)&feat, (void*)&ridx, (void*)&kp,
        (void*)&W1, (void*)&Wk, (void*)&W3,
        (void*)&g1, (void*)&b1, (void*)&g2, (void*)&b2, (void*)&g3, (void*)&b3,
        (void*)&out,
        (void*)&Wb, (void*)&T, (void*)&U, (void*)&T2, (void*)&X1,
        (void*)&part, (void*)&stats
    };
    hipLaunchCooperativeKernel((const void*)k_mega, dim3((unsigned)grid), dim3(256),
                               args, 0, stream);
}

// Round 7
// 517.509 us; speedup vs baseline: 1.7210x; 1.7210x over previous
//
#include <hip/hip_runtime.h>

#define N_PTS 16384
#define NH 16
#define NC 192
#define NK 43
#define ND 2
#define BN_EPS 1e-5f

typedef __attribute__((ext_vector_type(8))) short bf16x8;
typedef __attribute__((ext_vector_type(4))) float f32x4;

static __device__ __forceinline__ short f2bf(float f) {
    union { float f; unsigned u; } x; x.f = f;
    unsigned r = x.u + (0x7fffu + ((x.u >> 16) & 1u));   // RNE
    return (short)(r >> 16);
}
static __device__ __forceinline__ float bf2f(short s) {
    union { unsigned u; float f; } x; x.u = ((unsigned)(unsigned short)s) << 16;
    return x.f;
}

// ---------- weight shuffle to MFMA B-frag layout + zero stat accumulators ----------
// Frag element (nt, ks, lane, j) = W[k = ks*32 + (lane>>4)*8 + j][n = nt*16 + (lane&15)]
// Per-layer region: W1b[36864] | Wkb[12288] | W3b[36864] (shorts), stride 86016.
__global__ __launch_bounds__(64) void k_wfrag(const float* __restrict__ W1,
                                              const float* __restrict__ Wk,
                                              const float* __restrict__ W3,
                                              short* __restrict__ Wb,
                                              float* __restrict__ accz) {
    int gtid = blockIdx.x * 64 + threadIdx.x;
    if (gtid < 2400) accz[gtid] = 0.f;     // 6 sites x (384 sums + counter + pad)

    int b = blockIdx.x;
    int d = b / 168, r = b % 168;
    const float* src; short* dst; int kb, Ks, tile;
    if (r < 72)      { src = W1 + d * NC * NC; dst = Wb + d * 86016;         kb = 6; Ks = NC; tile = r; }
    else if (r < 96) { src = Wk + d * NK * NC; dst = Wb + d * 86016 + 36864; kb = 2; Ks = NK; tile = r - 72; }
    else             { src = W3 + d * NC * NC; dst = Wb + d * 86016 + 49152; kb = 6; Ks = NC; tile = r - 96; }
    int nt = tile / kb, ks = tile % kb;
    int lane = threadIdx.x, quad = lane >> 4, cl = lane & 15;
    bf16x8 vv;
#pragma unroll
    for (int j = 0; j < 8; ++j) {
        int k = ks * 32 + quad * 8 + j;
        vv[j] = (k < Ks) ? f2bf(src[k * NC + nt * 16 + cl]) : (short)0;
    }
    *(bf16x8*)(dst + ((nt * kb + ks) * 64 + lane) * 8) = vv;
}

// epilogue helper used by producers: block partials -> atomics -> last-block finalize
static __device__ __forceinline__ void stats_epilogue(
    float red[4][384], int* lastf, float* __restrict__ gacc, int* __restrict__ cnt,
    const float* __restrict__ g, const float* __restrict__ bb, float* __restrict__ st,
    int tid, unsigned nblocks) {
    __syncthreads();
    for (int t = tid; t < 384; t += 256)
        atomicAdd(gacc + t, red[0][t] + red[1][t] + red[2][t] + red[3][t]);
    __threadfence();
    if (tid == 0) *lastf = (atomicAdd(cnt, 1) == (int)nblocks - 1);
    __syncthreads();
    if (*lastf && tid < 192) {
        float s  = atomicAdd(gacc + tid, 0.f);          // device-scope atomic read
        float sq = atomicAdd(gacc + 192 + tid, 0.f);
        float m = s * (1.f / N_PTS);
        float var = sq * (1.f / N_PTS) - m * m;
        float a = rsqrtf(var + BN_EPS) * g[tid];
        st[tid] = a;
        st[192 + tid] = bb[tid] - m * a;
    }
}

// ---------- GEMM1: T(bf16) = A @ W1 with A = feat (L0) or relu(feat + bn3_L0(T2)) (L1) ----------
// 256 blocks x 256 thr; wave = 16 rows; BN1 stats finalized in-kernel (last block).
__global__ __launch_bounds__(256) void k_gemm1(const float* __restrict__ feat,
                                               const short* __restrict__ T2prev,
                                               const float* __restrict__ st3prev,
                                               float* __restrict__ X1,
                                               const short* __restrict__ W1b,
                                               short* __restrict__ T,
                                               float* __restrict__ gacc, int* __restrict__ cnt,
                                               const float* __restrict__ g,
                                               const float* __restrict__ bb,
                                               float* __restrict__ st) {
    __shared__ float red[4][384];
    __shared__ int lastf;
    const int tid = threadIdx.x;
    const int wave = tid >> 6, lane = tid & 63;
    const int quad = lane >> 4, cl = lane & 15;
    const int r0 = blockIdx.x * 64 + wave * 16;
    const int row = r0 + cl;

    f32x4 acc[12];
#pragma unroll
    for (int nt = 0; nt < 12; ++nt) acc[nt] = (f32x4){0.f, 0.f, 0.f, 0.f};

#pragma unroll
    for (int ks = 0; ks < 6; ++ks) {
        const int k0 = ks * 32 + quad * 8;
        const float* ap = feat + row * NC + k0;
        float4 a0 = *(const float4*)ap;
        float4 a1v = *(const float4*)(ap + 4);
        float x[8] = {a0.x, a0.y, a0.z, a0.w, a1v.x, a1v.y, a1v.z, a1v.w};
        if (T2prev) {   // fused skip: x = relu(feat + bn3_L0(T2)); store X1
            bf16x8 t2 = *(const bf16x8*)(T2prev + row * NC + k0);
            float4 pa0 = *(const float4*)(st3prev + k0), pa1 = *(const float4*)(st3prev + k0 + 4);
            float4 ps0 = *(const float4*)(st3prev + 192 + k0), ps1 = *(const float4*)(st3prev + 192 + k0 + 4);
            float pav[8] = {pa0.x, pa0.y, pa0.z, pa0.w, pa1.x, pa1.y, pa1.z, pa1.w};
            float psv[8] = {ps0.x, ps0.y, ps0.z, ps0.w, ps1.x, ps1.y, ps1.z, ps1.w};
#pragma unroll
            for (int j = 0; j < 8; ++j)
                x[j] = fmaxf(x[j] + fmaf(pav[j], bf2f(t2[j]), psv[j]), 0.f);
            *(float4*)(X1 + row * NC + k0)     = (float4){x[0], x[1], x[2], x[3]};
            *(float4*)(X1 + row * NC + k0 + 4) = (float4){x[4], x[5], x[6], x[7]};
        }
        bf16x8 af;
#pragma unroll
        for (int j = 0; j < 8; ++j) af[j] = f2bf(x[j]);
#pragma unroll
        for (int nt = 0; nt < 12; ++nt) {
            bf16x8 bf = *(const bf16x8*)(W1b + ((nt * 6 + ks) * 64 + lane) * 8);
            acc[nt] = __builtin_amdgcn_mfma_f32_16x16x32_bf16(af, bf, acc[nt], 0, 0, 0);
        }
    }
#pragma unroll
    for (int nt = 0; nt < 12; ++nt) {
        int c = nt * 16 + cl;
        float s = 0.f, sq = 0.f;
#pragma unroll
        for (int r = 0; r < 4; ++r) {
            float v = acc[nt][r];
            T[(r0 + quad * 4 + r) * NC + c] = f2bf(v);
            s += v; sq = fmaf(v, v, sq);
        }
        s += __shfl_xor(s, 16); s += __shfl_xor(s, 32);
        sq += __shfl_xor(sq, 16); sq += __shfl_xor(sq, 32);
        if (quad == 0) { red[wave][c] = s; red[wave][192 + c] = sq; }
    }
    stats_epilogue(red, &lastf, gacc, cnt, g, bb, st, tid, gridDim.x);
}

// ---------- kpconv: U = sum_h (infl @ Wk)[h,c] * relu(bn1(T[ref[h]]))[h,c] ----------
// 1024 blocks x 256 thr; 4 points per wave; BN1 inline; BN2 stats in-kernel.
__global__ __launch_bounds__(256) void k_kpconv(const float* __restrict__ coord,
                                                const int* __restrict__ ridx,
                                                const float* __restrict__ kp,
                                                const short* __restrict__ Wkb,
                                                const short* __restrict__ T,
                                                const float* __restrict__ st1,
                                                short* __restrict__ U,
                                                float* __restrict__ gacc, int* __restrict__ cnt,
                                                const float* __restrict__ g,
                                                const float* __restrict__ bb,
                                                float* __restrict__ st2) {
    __shared__ __align__(16) short wk_s[12288];     // Wk B-frags, 24 KiB
    __shared__ float kp_s[64][4];
    __shared__ float red[4][384];
    __shared__ int lastf;

    const int tid = threadIdx.x;
    const int wave = tid >> 6, lane = tid & 63;
    const int quad = lane >> 4, cl = lane & 15;

    {
        const float4* src = (const float4*)Wkb;
        float4* dst = (float4*)wk_s;
        for (int j = tid; j < 1536; j += 256) dst[j] = src[j];
        if (tid < 64) {
            bool ok = tid < NK;
            kp_s[tid][0] = ok ? kp[tid * 3 + 0] : 0.f;
            kp_s[tid][1] = ok ? kp[tid * 3 + 1] : 0.f;
            kp_s[tid][2] = ok ? kp[tid * 3 + 2] : 0.f;
        }
    }
    __syncthreads();

    float a1r[12], s1r[12];
#pragma unroll
    for (int nt = 0; nt < 12; ++nt) {
        a1r[nt] = st1[nt * 16 + cl];
        s1r[nt] = st1[192 + nt * 16 + cl];
    }
    const unsigned short* Tu = (const unsigned short*)T;
    const int gw = blockIdx.x * 4 + wave;          // 0..4095

    float su[12], squ[12];
#pragma unroll
    for (int nt = 0; nt < 12; ++nt) { su[nt] = 0.f; squ[nt] = 0.f; }

    for (int pp = 0; pp < 4; ++pp) {
        const int n = gw * 4 + pp;
        int idh = 0; float nbx = 0.f, nby = 0.f, nbz = 0.f;
        if (lane < NH) {
            idh = ridx[n * NH + lane];
            nbx = coord[idh * 3 + 0] - coord[n * 3 + 0];
            nby = coord[idh * 3 + 1] - coord[n * 3 + 1];
            nbz = coord[idh * 3 + 2] - coord[n * 3 + 2];
        }
        const float nx = __shfl(nbx, cl), ny = __shfl(nby, cl), nz = __shfl(nbz, cl);
        int rowb[4];
#pragma unroll
        for (int r = 0; r < 4; ++r) rowb[r] = __shfl(idh, quad * 4 + r) * NC;

        // hoisted gather: 48 independent loads ahead of influence+MFMA
        unsigned short xv[12][4];
#pragma unroll
        for (int nt = 0; nt < 12; ++nt)
#pragma unroll
            for (int r = 0; r < 4; ++r)
                xv[nt][r] = Tu[rowb[r] + nt * 16 + cl];

        // influence A-fragments in registers: A[m = h = cl][k = ks*32+quad*8+j]
        bf16x8 af[2];
#pragma unroll
        for (int ks = 0; ks < 2; ++ks) {
#pragma unroll
            for (int j = 0; j < 8; ++j) {
                int k = ks * 32 + quad * 8 + j;
                float dx = nx - kp_s[k][0];
                float dy = ny - kp_s[k][1];
                float dz = nz - kp_s[k][2];
                float dist = sqrtf(fmaf(dx, dx, fmaf(dy, dy, dz * dz)));
                float w = fmaxf(1.f - dist, 0.f);   // SIGMA = 1
                if (k >= NK) w = 0.f;
                af[ks][j] = f2bf(w);
            }
        }
        f32x4 acc[12];
#pragma unroll
        for (int nt = 0; nt < 12; ++nt) {
            bf16x8 b0 = *(const bf16x8*)(wk_s + ((nt * 2 + 0) * 64 + lane) * 8);
            bf16x8 b1v = *(const bf16x8*)(wk_s + ((nt * 2 + 1) * 64 + lane) * 8);
            f32x4 z = (f32x4){0.f, 0.f, 0.f, 0.f};
            z = __builtin_amdgcn_mfma_f32_16x16x32_bf16(af[0], b0, z, 0, 0, 0);
            acc[nt] = __builtin_amdgcn_mfma_f32_16x16x32_bf16(af[1], b1v, z, 0, 0, 0);
        }
#pragma unroll
        for (int nt = 0; nt < 12; ++nt) {
            float u = 0.f;
#pragma unroll
            for (int r = 0; r < 4; ++r) {
                float t = bf2f((short)xv[nt][r]);
                float xr = fmaxf(fmaf(a1r[nt], t, s1r[nt]), 0.f);   // bn1+relu inline
                u = fmaf(acc[nt][r], xr, u);
            }
            u += __shfl_xor(u, 16);
            u += __shfl_xor(u, 32);
            if (quad == 0) U[n * NC + nt * 16 + cl] = f2bf(u);
            su[nt] += u; squ[nt] = fmaf(u, u, squ[nt]);
        }
    }
    if (quad == 0) {
#pragma unroll
        for (int nt = 0; nt < 12; ++nt) {
            red[wave][nt * 16 + cl] = su[nt];
            red[wave][192 + nt * 16 + cl] = squ[nt];
        }
    }
    stats_epilogue(red, &lastf, gacc, cnt, g, bb, st2, tid, gridDim.x);
}

// ---------- GEMM3: T2(bf16) = relu(bn2(U)) @ W3; BN3 stats in-kernel ----------
__global__ __launch_bounds__(256) void k_gemm3(const short* __restrict__ U,
                                               const float* __restrict__ st2,
                                               const short* __restrict__ W3b,
                                               short* __restrict__ T2,
                                               float* __restrict__ gacc, int* __restrict__ cnt,
                                               const float* __restrict__ g,
                                               const float* __restrict__ bb,
                                               float* __restrict__ st) {
    __shared__ float red[4][384];
    __shared__ int lastf;
    const int tid = threadIdx.x;
    const int wave = tid >> 6, lane = tid & 63;
    const int quad = lane >> 4, cl = lane & 15;
    const int r0 = blockIdx.x * 64 + wave * 16;
    const int row = r0 + cl;

    f32x4 acc[12];
#pragma unroll
    for (int nt = 0; nt < 12; ++nt) acc[nt] = (f32x4){0.f, 0.f, 0.f, 0.f};

#pragma unroll
    for (int ks = 0; ks < 6; ++ks) {
        const int k0 = ks * 32 + quad * 8;
        bf16x8 u8 = *(const bf16x8*)(U + row * NC + k0);
        float4 aa0 = *(const float4*)(st2 + k0), aa1 = *(const float4*)(st2 + k0 + 4);
        float4 ss0 = *(const float4*)(st2 + 192 + k0), ss1 = *(const float4*)(st2 + 192 + k0 + 4);
        float av[8] = {aa0.x, aa0.y, aa0.z, aa0.w, aa1.x, aa1.y, aa1.z, aa1.w};
        float sv[8] = {ss0.x, ss0.y, ss0.z, ss0.w, ss1.x, ss1.y, ss1.z, ss1.w};
        bf16x8 af;
#pragma unroll
        for (int j = 0; j < 8; ++j)
            af[j] = f2bf(fmaxf(fmaf(av[j], bf2f(u8[j]), sv[j]), 0.f));
#pragma unroll
        for (int nt = 0; nt < 12; ++nt) {
            bf16x8 bf = *(const bf16x8*)(W3b + ((nt * 6 + ks) * 64 + lane) * 8);
            acc[nt] = __builtin_amdgcn_mfma_f32_16x16x32_bf16(af, bf, acc[nt], 0, 0, 0);
        }
    }
#pragma unroll
    for (int nt = 0; nt < 12; ++nt) {
        int c = nt * 16 + cl;
        float s = 0.f, sq = 0.f;
#pragma unroll
        for (int r = 0; r < 4; ++r) {
            float v = acc[nt][r];
            T2[(r0 + quad * 4 + r) * NC + c] = f2bf(v);
            s += v; sq = fmaf(v, v, sq);
        }
        s += __shfl_xor(s, 16); s += __shfl_xor(s, 32);
        sq += __shfl_xor(sq, 16); sq += __shfl_xor(sq, 32);
        if (quad == 0) { red[wave][c] = s; red[wave][192 + c] = sq; }
    }
    stats_epilogue(red, &lastf, gacc, cnt, g, bb, st, tid, gridDim.x);
}

// ---------- final: out = relu(X1 + bn3_L1(T2)) ----------
__global__ __launch_bounds__(256) void k_final(const short* __restrict__ T2,
                                               const float* __restrict__ st3,
                                               const float* __restrict__ X1,
                                               float* __restrict__ out) {
    const int i = blockIdx.x * 256 + threadIdx.x;   // grid covers N*NC/8 exactly
    const int c0 = (i * 8) % 192;
    bf16x8 t2 = *(const bf16x8*)(T2 + (long)i * 8);
    float4 x0 = *(const float4*)(X1 + (long)i * 8);
    float4 x1 = *(const float4*)(X1 + (long)i * 8 + 4);
    float4 aa0 = *(const float4*)(st3 + c0), aa1 = *(const float4*)(st3 + c0 + 4);
    float4 ss0 = *(const float4*)(st3 + 192 + c0), ss1 = *(const float4*)(st3 + 192 + c0 + 4);
    float4 o0, o1;
    o0.x = fmaxf(x0.x + fmaf(aa0.x, bf2f(t2[0]), ss0.x), 0.f);
    o0.y = fmaxf(x0.y + fmaf(aa0.y, bf2f(t2[1]), ss0.y), 0.f);
    o0.z = fmaxf(x0.z + fmaf(aa0.z, bf2f(t2[2]), ss0.z), 0.f);
    o0.w = fmaxf(x0.w + fmaf(aa0.w, bf2f(t2[3]), ss0.w), 0.f);
    o1.x = fmaxf(x1.x + fmaf(aa1.x, bf2f(t2[4]), ss1.x), 0.f);
    o1.y = fmaxf(x1.y + fmaf(aa1.y, bf2f(t2[5]), ss1.y), 0.f);
    o1.z = fmaxf(x1.z + fmaf(aa1.z, bf2f(t2[6]), ss1.z), 0.f);
    o1.w = fmaxf(x1.w + fmaf(aa1.w, bf2f(t2[7]), ss1.w), 0.f);
    *(float4*)(out + (long)i * 8)     = o0;
    *(float4*)(out + (long)i * 8 + 4) = o1;
}

extern "C" void kernel_launch(void* const* d_in, const int* in_sizes, int n_in,
                              void* d_out, int out_size, void* d_ws, size_t ws_size,
                              hipStream_t stream) {
    const float* coord = (const float*)d_in[0];
    const float* feat  = (const float*)d_in[1];
    const int*   ridx  = (const int*)d_in[2];
    const float* kp    = (const float*)d_in[3];
    const float* W1    = (const float*)d_in[4];
    const float* Wk    = (const float*)d_in[5];
    const float* W3    = (const float*)d_in[6];
    const float* g1    = (const float*)d_in[7];
    const float* b1    = (const float*)d_in[8];
    const float* g2    = (const float*)d_in[9];
    const float* b2    = (const float*)d_in[10];
    const float* g3    = (const float*)d_in[11];
    const float* b3    = (const float*)d_in[12];
    float* out = (float*)d_out;

    // ws (floats): X1 | acc[6*400] | stats[6*384] | shorts: T | U | T2 | Wb  ~= 31.8 MB
    float* X1    = (float*)d_ws;
    float* accb  = X1 + N_PTS * NC;
    float* stats = accb + 2400;
    short* T  = (short*)(stats + 2304);
    short* U  = T + N_PTS * NC;
    short* T2 = U + N_PTS * NC;
    short* Wb = T2 + N_PTS * NC;

    k_wfrag<<<336, 64, 0, stream>>>(W1, Wk, W3, Wb, accb);

    for (int d = 0; d < ND; ++d) {
        const short* W1b = Wb + d * 86016;
        const short* Wkb = W1b + 36864;
        const short* W3b = W1b + 49152;
        float* st1 = stats + (d * 3 + 0) * 384;
        float* st2 = stats + (d * 3 + 1) * 384;
        float* st3 = stats + (d * 3 + 2) * 384;
        float* ac1 = accb + (d * 3 + 0) * 400;
        float* ac2 = accb + (d * 3 + 1) * 400;
        float* ac3 = accb + (d * 3 + 2) * 400;
        int* cn1 = (int*)(ac1 + 384);
        int* cn2 = (int*)(ac2 + 384);
        int* cn3 = (int*)(ac3 + 384);

        k_gemm1<<<256, 256, 0, stream>>>(feat,
                                         d ? T2 : (short*)nullptr,
                                         stats + 2 * 384,   // bn3 of layer 0
                                         X1, W1b, T, ac1, cn1,
                                         g1 + d * NC, b1 + d * NC, st1);
        k_kpconv<<<1024, 256, 0, stream>>>(coord, ridx, kp, Wkb, T, st1, U, ac2, cn2,
                                           g2 + d * NC, b2 + d * NC, st2);
        k_gemm3<<<256, 256, 0, stream>>>(U, st2, W3b, T2, ac3, cn3,
                                         g3 + d * NC, b3 + d * NC, st3);
    }
    k_final<<<N_PTS * NC / 8 / 256, 256, 0, stream>>>(T2, stats + 5 * 384, X1, out);
}

// Round 8
// 289.184 us; speedup vs baseline: 3.0798x; 1.7895x over previous
//
#include <hip/hip_runtime.h>

#define N_PTS 16384
#define NH 16
#define NC 192
#define NK 43
#define ND 2
#define BN_EPS 1e-5f

typedef __attribute__((ext_vector_type(8))) short bf16x8;
typedef __attribute__((ext_vector_type(4))) float f32x4;

static __device__ __forceinline__ short f2bf(float f) {
    union { float f; unsigned u; } x; x.f = f;
    unsigned r = x.u + (0x7fffu + ((x.u >> 16) & 1u));   // RNE
    return (short)(r >> 16);
}
static __device__ __forceinline__ float bf2f(short s) {
    union { unsigned u; float f; } x; x.u = ((unsigned)(unsigned short)s) << 16;
    return x.f;
}

// ---------- weight shuffle to MFMA B-frag layout ----------
// Frag element (nt, ks, lane, j) = W[k = ks*32 + (lane>>4)*8 + j][n = nt*16 + (lane&15)]
// Per-layer region: W1b[36864] | Wkb[12288] | W3b[36864] (shorts), stride 86016.
__global__ __launch_bounds__(64) void k_wfrag(const float* __restrict__ W1,
                                              const float* __restrict__ Wk,
                                              const float* __restrict__ W3,
                                              short* __restrict__ Wb) {
    int b = blockIdx.x;
    int d = b / 168, r = b % 168;
    const float* src; short* dst; int kb, Ks, tile;
    if (r < 72)      { src = W1 + d * NC * NC; dst = Wb + d * 86016;         kb = 6; Ks = NC; tile = r; }
    else if (r < 96) { src = Wk + d * NK * NC; dst = Wb + d * 86016 + 36864; kb = 2; Ks = NK; tile = r - 72; }
    else             { src = W3 + d * NC * NC; dst = Wb + d * 86016 + 49152; kb = 6; Ks = NC; tile = r - 96; }
    int nt = tile / kb, ks = tile % kb;
    int lane = threadIdx.x, quad = lane >> 4, cl = lane & 15;
    bf16x8 vv;
#pragma unroll
    for (int j = 0; j < 8; ++j) {
        int k = ks * 32 + quad * 8 + j;
        vv[j] = (k < Ks) ? f2bf(src[k * NC + nt * 16 + cl]) : (short)0;
    }
    *(bf16x8*)(dst + ((nt * kb + ks) * 64 + lane) * 8) = vv;
}

// ---------- stats finalize: a = g*rsqrt(var+eps), s = b - m*a ----------
// grid = 192 blocks (one channel each), 128 threads: wave0 -> sum, wave1 -> sumsq.
__global__ __launch_bounds__(128) void k_stat2(const float* __restrict__ part, int nb,
                                               const float* __restrict__ g,
                                               const float* __restrict__ b,
                                               float* __restrict__ a_out,
                                               float* __restrict__ s_out) {
    __shared__ float red2[2];
    const int c = blockIdx.x;
    const int tid = threadIdx.x;
    const int lane = tid & 63;
    const int half = tid >> 6;                 // 0: sum, 1: sumsq
    const float* src = part + (half ? 192 + c : c);
    float s = 0.f;
    for (int i = lane; i < nb; i += 64) s += src[i * 384];
    s += __shfl_xor(s, 1);  s += __shfl_xor(s, 2);  s += __shfl_xor(s, 4);
    s += __shfl_xor(s, 8);  s += __shfl_xor(s, 16); s += __shfl_xor(s, 32);
    if (lane == 0) red2[half] = s;
    __syncthreads();
    if (tid == 0) {
        float m = red2[0] * (1.f / N_PTS);
        float var = red2[1] * (1.f / N_PTS) - m * m;
        float rs = rsqrtf(var + BN_EPS);
        float a = rs * g[c];
        a_out[c] = a;
        s_out[c] = b[c] - m * a;
    }
}

// ---------- per-channel partial sums of a bf16 [N,C] buffer (BN2 stats stage 1) ----------
__global__ __launch_bounds__(192) void k_stat1b(const short* __restrict__ A,
                                                float* __restrict__ part) {
    const int c = threadIdx.x, b = blockIdx.x;
    const short* p = A + b * 16 * NC + c;
    float s = 0.f, sq = 0.f;
#pragma unroll
    for (int r = 0; r < 16; ++r) {
        float v = bf2f(p[r * NC]);
        s += v; sq = fmaf(v, v, sq);
    }
    part[b * 384 + c] = s;
    part[b * 384 + 192 + c] = sq;
}

// ---------- GEMM1: T(bf16) = A @ W1; A = feat (L0) or relu(feat + bn3_L0(T2)) (L1) ----------
// 256 blocks x 256 thr; wave = 16 rows; partials -> part (plain stores).
__global__ __launch_bounds__(256) void k_gemm1(const float* __restrict__ feat,
                                               const short* __restrict__ T2prev,
                                               const float* __restrict__ st3prev,
                                               float* __restrict__ X1,
                                               const short* __restrict__ W1b,
                                               short* __restrict__ T,
                                               float* __restrict__ part) {
    __shared__ float red[4][384];
    const int tid = threadIdx.x;
    const int wave = tid >> 6, lane = tid & 63;
    const int quad = lane >> 4, cl = lane & 15;
    const int r0 = blockIdx.x * 64 + wave * 16;
    const int row = r0 + cl;

    f32x4 acc[12];
#pragma unroll
    for (int nt = 0; nt < 12; ++nt) acc[nt] = (f32x4){0.f, 0.f, 0.f, 0.f};

#pragma unroll
    for (int ks = 0; ks < 6; ++ks) {
        const int k0 = ks * 32 + quad * 8;
        const float* ap = feat + row * NC + k0;
        float4 a0 = *(const float4*)ap;
        float4 a1v = *(const float4*)(ap + 4);
        float x[8] = {a0.x, a0.y, a0.z, a0.w, a1v.x, a1v.y, a1v.z, a1v.w};
        if (T2prev) {   // fused skip: x = relu(feat + bn3_L0(T2)); store X1
            bf16x8 t2 = *(const bf16x8*)(T2prev + row * NC + k0);
            float4 pa0 = *(const float4*)(st3prev + k0), pa1 = *(const float4*)(st3prev + k0 + 4);
            float4 ps0 = *(const float4*)(st3prev + 192 + k0), ps1 = *(const float4*)(st3prev + 192 + k0 + 4);
            float pav[8] = {pa0.x, pa0.y, pa0.z, pa0.w, pa1.x, pa1.y, pa1.z, pa1.w};
            float psv[8] = {ps0.x, ps0.y, ps0.z, ps0.w, ps1.x, ps1.y, ps1.z, ps1.w};
#pragma unroll
            for (int j = 0; j < 8; ++j)
                x[j] = fmaxf(x[j] + fmaf(pav[j], bf2f(t2[j]), psv[j]), 0.f);
            *(float4*)(X1 + row * NC + k0)     = (float4){x[0], x[1], x[2], x[3]};
            *(float4*)(X1 + row * NC + k0 + 4) = (float4){x[4], x[5], x[6], x[7]};
        }
        bf16x8 af;
#pragma unroll
        for (int j = 0; j < 8; ++j) af[j] = f2bf(x[j]);
#pragma unroll
        for (int nt = 0; nt < 12; ++nt) {
            bf16x8 bf = *(const bf16x8*)(W1b + ((nt * 6 + ks) * 64 + lane) * 8);
            acc[nt] = __builtin_amdgcn_mfma_f32_16x16x32_bf16(af, bf, acc[nt], 0, 0, 0);
        }
    }
#pragma unroll
    for (int nt = 0; nt < 12; ++nt) {
        int c = nt * 16 + cl;
        float s = 0.f, sq = 0.f;
#pragma unroll
        for (int r = 0; r < 4; ++r) {
            float v = acc[nt][r];
            T[(r0 + quad * 4 + r) * NC + c] = f2bf(v);
            s += v; sq = fmaf(v, v, sq);
        }
        s += __shfl_xor(s, 16); s += __shfl_xor(s, 32);
        sq += __shfl_xor(sq, 16); sq += __shfl_xor(sq, 32);
        if (quad == 0) { red[wave][c] = s; red[wave][192 + c] = sq; }
    }
    __syncthreads();
    for (int t = tid; t < 384; t += 256)
        part[blockIdx.x * 384 + t] = red[0][t] + red[1][t] + red[2][t] + red[3][t];
}

// ---------- kpconv: U = sum_h (infl @ Wk)[h,c] * relu(bn1(T[ref[h]]))[h,c] ----------
// grid 4096 x 256 thr, ONE POINT PER WAVE (round-5 proven shape). BN1 inline,
// a/s staged in LDS (read per use -> no long-lived VGPR array). No stats here.
__global__ __launch_bounds__(256) void k_kpconv(const float* __restrict__ coord,
                                                const int* __restrict__ ridx,
                                                const float* __restrict__ kp,
                                                const short* __restrict__ Wkb,
                                                const short* __restrict__ T,
                                                const float* __restrict__ st1,
                                                short* __restrict__ U) {
    __shared__ __align__(16) short wk_s[12288];     // 24 KiB Wk B-frags
    __shared__ float kp_s[64][4];
    __shared__ float a1s[192], s1s[192];

    const int tid = threadIdx.x;
    {
        const float4* src = (const float4*)Wkb;
        float4* dst = (float4*)wk_s;
        for (int j = tid; j < 1536; j += 256) dst[j] = src[j];
        if (tid < 64) {
            bool ok = tid < NK;
            kp_s[tid][0] = ok ? kp[tid * 3 + 0] : 0.f;
            kp_s[tid][1] = ok ? kp[tid * 3 + 1] : 0.f;
            kp_s[tid][2] = ok ? kp[tid * 3 + 2] : 0.f;
        }
        if (tid < 192) { a1s[tid] = st1[tid]; s1s[tid] = st1[192 + tid]; }
    }
    __syncthreads();

    const int wave = tid >> 6, lane = tid & 63;
    const int quad = lane >> 4, cl = lane & 15;
    const int n = blockIdx.x * 4 + wave;

    // per-point setup: lanes 0..15 load neighbor idx + relative coords, bcast via shfl
    int idh = 0; float nbx = 0.f, nby = 0.f, nbz = 0.f;
    if (lane < NH) {
        idh = ridx[n * NH + lane];
        float cx = coord[n * 3 + 0], cy = coord[n * 3 + 1], cz = coord[n * 3 + 2];
        nbx = coord[idh * 3 + 0] - cx;
        nby = coord[idh * 3 + 1] - cy;
        nbz = coord[idh * 3 + 2] - cz;
    }
    const float nx = __shfl(nbx, cl), ny = __shfl(nby, cl), nz = __shfl(nbz, cl);
    int rowb[4];
#pragma unroll
    for (int r = 0; r < 4; ++r) rowb[r] = __shfl(idh, quad * 4 + r) * NC;

    // ---- hoisted gather: all 48 loads issued before influence+MFMA compute ----
    unsigned short xv[12][4];
    const unsigned short* Tu = (const unsigned short*)T;
#pragma unroll
    for (int nt = 0; nt < 12; ++nt)
#pragma unroll
        for (int r = 0; r < 4; ++r)
            xv[nt][r] = Tu[rowb[r] + nt * 16 + cl];

    // ---- influence A-fragments in registers: A[m = h = cl][k = ks*32+quad*8+j]
    bf16x8 af[2];
#pragma unroll
    for (int ks = 0; ks < 2; ++ks) {
#pragma unroll
        for (int j = 0; j < 8; ++j) {
            int k = ks * 32 + quad * 8 + j;
            float dx = nx - kp_s[k][0];
            float dy = ny - kp_s[k][1];
            float dz = nz - kp_s[k][2];
            float d = sqrtf(fmaf(dx, dx, fmaf(dy, dy, dz * dz)));
            float w = fmaxf(1.f - d, 0.f);         // SIGMA = 1
            if (k >= NK) w = 0.f;
            af[ks][j] = f2bf(w);
        }
    }

    // ---- A = infl @ Wk via MFMA (12 n-tiles x 2 k-steps), B-frags from LDS
    f32x4 acc[12];
#pragma unroll
    for (int nt = 0; nt < 12; ++nt) {
        bf16x8 b0 = *(const bf16x8*)(wk_s + ((nt * 2 + 0) * 64 + lane) * 8);
        bf16x8 b1v = *(const bf16x8*)(wk_s + ((nt * 2 + 1) * 64 + lane) * 8);
        f32x4 z = (f32x4){0.f, 0.f, 0.f, 0.f};
        z = __builtin_amdgcn_mfma_f32_16x16x32_bf16(af[0], b0, z, 0, 0, 0);
        acc[nt] = __builtin_amdgcn_mfma_f32_16x16x32_bf16(af[1], b1v, z, 0, 0, 0);
    }

    // ---- aggregate: U[n,c] = sum_h acc[h,c] * relu(bn1(xv[h,c]))
#pragma unroll
    for (int nt = 0; nt < 12; ++nt) {
        const float a1c = a1s[nt * 16 + cl], s1c = s1s[nt * 16 + cl];
        float u = 0.f;
#pragma unroll
        for (int r = 0; r < 4; ++r) {
            float t = bf2f((short)xv[nt][r]);
            float x = fmaxf(fmaf(a1c, t, s1c), 0.f);
            u = fmaf(acc[nt][r], x, u);
        }
        u += __shfl_xor(u, 16);
        u += __shfl_xor(u, 32);
        if (quad == 0) U[n * NC + nt * 16 + cl] = f2bf(u);
    }
}

// ---------- GEMM3: T2(bf16) = relu(bn2(U)) @ W3; partials -> part ----------
__global__ __launch_bounds__(256) void k_gemm3(const short* __restrict__ U,
                                               const float* __restrict__ st2,
                                               const short* __restrict__ W3b,
                                               short* __restrict__ T2,
                                               float* __restrict__ part) {
    __shared__ float red[4][384];
    const int tid = threadIdx.x;
    const int wave = tid >> 6, lane = tid & 63;
    const int quad = lane >> 4, cl = lane & 15;
    const int r0 = blockIdx.x * 64 + wave * 16;
    const int row = r0 + cl;

    f32x4 acc[12];
#pragma unroll
    for (int nt = 0; nt < 12; ++nt) acc[nt] = (f32x4){0.f, 0.f, 0.f, 0.f};

#pragma unroll
    for (int ks = 0; ks < 6; ++ks) {
        const int k0 = ks * 32 + quad * 8;
        bf16x8 u8 = *(const bf16x8*)(U + row * NC + k0);
        float4 aa0 = *(const float4*)(st2 + k0), aa1 = *(const float4*)(st2 + k0 + 4);
        float4 ss0 = *(const float4*)(st2 + 192 + k0), ss1 = *(const float4*)(st2 + 192 + k0 + 4);
        float av[8] = {aa0.x, aa0.y, aa0.z, aa0.w, aa1.x, aa1.y, aa1.z, aa1.w};
        float sv[8] = {ss0.x, ss0.y, ss0.z, ss0.w, ss1.x, ss1.y, ss1.z, ss1.w};
        bf16x8 af;
#pragma unroll
        for (int j = 0; j < 8; ++j)
            af[j] = f2bf(fmaxf(fmaf(av[j], bf2f(u8[j]), sv[j]), 0.f));
#pragma unroll
        for (int nt = 0; nt < 12; ++nt) {
            bf16x8 bf = *(const bf16x8*)(W3b + ((nt * 6 + ks) * 64 + lane) * 8);
            acc[nt] = __builtin_amdgcn_mfma_f32_16x16x32_bf16(af, bf, acc[nt], 0, 0, 0);
        }
    }
#pragma unroll
    for (int nt = 0; nt < 12; ++nt) {
        int c = nt * 16 + cl;
        float s = 0.f, sq = 0.f;
#pragma unroll
        for (int r = 0; r < 4; ++r) {
            float v = acc[nt][r];
            T2[(r0 + quad * 4 + r) * NC + c] = f2bf(v);
            s += v; sq = fmaf(v, v, sq);
        }
        s += __shfl_xor(s, 16); s += __shfl_xor(s, 32);
        sq += __shfl_xor(sq, 16); sq += __shfl_xor(sq, 32);
        if (quad == 0) { red[wave][c] = s; red[wave][192 + c] = sq; }
    }
    __syncthreads();
    for (int t = tid; t < 384; t += 256)
        part[blockIdx.x * 384 + t] = red[0][t] + red[1][t] + red[2][t] + red[3][t];
}

// ---------- final: out = relu(X1 + bn3_L1(T2)) ----------
__global__ __launch_bounds__(256) void k_final(const short* __restrict__ T2,
                                               const float* __restrict__ st3,
                                               const float* __restrict__ X1,
                                               float* __restrict__ out) {
    const int i = blockIdx.x * 256 + threadIdx.x;   // grid covers N*NC/8 exactly
    const int c0 = (i * 8) % 192;
    bf16x8 t2 = *(const bf16x8*)(T2 + (long)i * 8);
    float4 x0 = *(const float4*)(X1 + (long)i * 8);
    float4 x1 = *(const float4*)(X1 + (long)i * 8 + 4);
    float4 aa0 = *(const float4*)(st3 + c0), aa1 = *(const float4*)(st3 + c0 + 4);
    float4 ss0 = *(const float4*)(st3 + 192 + c0), ss1 = *(const float4*)(st3 + 192 + c0 + 4);
    float4 o0, o1;
    o0.x = fmaxf(x0.x + fmaf(aa0.x, bf2f(t2[0]), ss0.x), 0.f);
    o0.y = fmaxf(x0.y + fmaf(aa0.y, bf2f(t2[1]), ss0.y), 0.f);
    o0.z = fmaxf(x0.z + fmaf(aa0.z, bf2f(t2[2]), ss0.z), 0.f);
    o0.w = fmaxf(x0.w + fmaf(aa0.w, bf2f(t2[3]), ss0.w), 0.f);
    o1.x = fmaxf(x1.x + fmaf(aa1.x, bf2f(t2[4]), ss1.x), 0.f);
    o1.y = fmaxf(x1.y + fmaf(aa1.y, bf2f(t2[5]), ss1.y), 0.f);
    o1.z = fmaxf(x1.z + fmaf(aa1.z, bf2f(t2[6]), ss1.z), 0.f);
    o1.w = fmaxf(x1.w + fmaf(aa1.w, bf2f(t2[7]), ss1.w), 0.f);
    *(float4*)(out + (long)i * 8)     = o0;
    *(float4*)(out + (long)i * 8 + 4) = o1;
}

extern "C" void kernel_launch(void* const* d_in, const int* in_sizes, int n_in,
                              void* d_out, int out_size, void* d_ws, size_t ws_size,
                              hipStream_t stream) {
    const float* coord = (const float*)d_in[0];
    const float* feat  = (const float*)d_in[1];
    const int*   ridx  = (const int*)d_in[2];
    const float* kp    = (const float*)d_in[3];
    const float* W1    = (const float*)d_in[4];
    const float* Wk    = (const float*)d_in[5];
    const float* W3    = (const float*)d_in[6];
    const float* g1    = (const float*)d_in[7];
    const float* b1    = (const float*)d_in[8];
    const float* g2    = (const float*)d_in[9];
    const float* b2    = (const float*)d_in[10];
    const float* g3    = (const float*)d_in[11];
    const float* b3    = (const float*)d_in[12];
    float* out = (float*)d_out;

    // ws (floats): X1 | part[1024*384] | stats[6*384] | shorts: T | U | T2 | Wb  ~= 32 MB
    float* X1    = (float*)d_ws;
    float* part  = X1 + N_PTS * NC;
    float* stats = part + 1024 * 384;
    short* T  = (short*)(stats + 2304);
    short* U  = T + N_PTS * NC;
    short* T2 = U + N_PTS * NC;
    short* Wb = T2 + N_PTS * NC;

    k_wfrag<<<336, 64, 0, stream>>>(W1, Wk, W3, Wb);

    for (int d = 0; d < ND; ++d) {
        const short* W1b = Wb + d * 86016;
        const short* Wkb = W1b + 36864;
        const short* W3b = W1b + 49152;
        float* st1 = stats + (d * 3 + 0) * 384;
        float* st2 = stats + (d * 3 + 1) * 384;
        float* st3 = stats + (d * 3 + 2) * 384;

        k_gemm1<<<256, 256, 0, stream>>>(feat,
                                         d ? T2 : (short*)nullptr,
                                         stats + 2 * 384,    // bn3 of layer 0
                                         X1, W1b, T, part);
        k_stat2<<<192, 128, 0, stream>>>(part, 256, g1 + d * NC, b1 + d * NC, st1, st1 + 192);
        k_kpconv<<<N_PTS / 4, 256, 0, stream>>>(coord, ridx, kp, Wkb, T, st1, U);
        k_stat1b<<<1024, 192, 0, stream>>>(U, part);
        k_stat2<<<192, 128, 0, stream>>>(part, 1024, g2 + d * NC, b2 + d * NC, st2, st2 + 192);
        k_gemm3<<<256, 256, 0, stream>>>(U, st2, W3b, T2, part);
        k_stat2<<<192, 128, 0, stream>>>(part, 256, g3 + d * NC, b3 + d * NC, st3, st3 + 192);
    }
    k_final<<<N_PTS * NC / 8 / 256, 256, 0, stream>>>(T2, stats + 5 * 384, X1, out);
}

// Round 9
// 264.218 us; speedup vs baseline: 3.3708x; 1.0945x over previous
//
#include <hip/hip_runtime.h>

#define N_PTS 16384
#define NH 16
#define NC 192
#define NK 43
#define ND 2
#define BN_EPS 1e-5f

typedef __attribute__((ext_vector_type(8))) short bf16x8;
typedef __attribute__((ext_vector_type(4))) float f32x4;

static __device__ __forceinline__ short f2bf(float f) {
    union { float f; unsigned u; } x; x.f = f;
    unsigned r = x.u + (0x7fffu + ((x.u >> 16) & 1u));   // RNE
    return (short)(r >> 16);
}
static __device__ __forceinline__ float bf2f(short s) {
    union { unsigned u; float f; } x; x.u = ((unsigned)(unsigned short)s) << 16;
    return x.f;
}

// ---------- weight shuffle to MFMA B-frag layout ----------
// Frag element (nt, ks, lane, j) = W[k = ks*32 + (lane>>4)*8 + j][n = nt*16 + (lane&15)]
// Per-layer region: W1b[36864] | Wkb[12288] | W3b[36864] (shorts), stride 86016.
__global__ __launch_bounds__(64) void k_wfrag(const float* __restrict__ W1,
                                              const float* __restrict__ Wk,
                                              const float* __restrict__ W3,
                                              short* __restrict__ Wb) {
    int b = blockIdx.x;
    int d = b / 168, r = b % 168;
    const float* src; short* dst; int kb, Ks, tile;
    if (r < 72)      { src = W1 + d * NC * NC; dst = Wb + d * 86016;         kb = 6; Ks = NC; tile = r; }
    else if (r < 96) { src = Wk + d * NK * NC; dst = Wb + d * 86016 + 36864; kb = 2; Ks = NK; tile = r - 72; }
    else             { src = W3 + d * NC * NC; dst = Wb + d * 86016 + 49152; kb = 6; Ks = NC; tile = r - 96; }
    int nt = tile / kb, ks = tile % kb;
    int lane = threadIdx.x, quad = lane >> 4, cl = lane & 15;
    bf16x8 vv;
#pragma unroll
    for (int j = 0; j < 8; ++j) {
        int k = ks * 32 + quad * 8 + j;
        vv[j] = (k < Ks) ? f2bf(src[k * NC + nt * 16 + cl]) : (short)0;
    }
    *(bf16x8*)(dst + ((nt * kb + ks) * 64 + lane) * 8) = vv;
}

// ---------- stats finalize: a = g*rsqrt(var+eps), s = b - m*a ----------
// grid = 192 blocks (one channel each), 128 threads: wave0 -> sum, wave1 -> sumsq.
__global__ __launch_bounds__(128) void k_stat2(const float* __restrict__ part, int nb,
                                               const float* __restrict__ g,
                                               const float* __restrict__ b,
                                               float* __restrict__ a_out,
                                               float* __restrict__ s_out) {
    __shared__ float red2[2];
    const int c = blockIdx.x;
    const int tid = threadIdx.x;
    const int lane = tid & 63;
    const int half = tid >> 6;                 // 0: sum, 1: sumsq
    const float* src = part + (half ? 192 + c : c);
    float s = 0.f;
    for (int i = lane; i < nb; i += 64) s += src[i * 384];
    s += __shfl_xor(s, 1);  s += __shfl_xor(s, 2);  s += __shfl_xor(s, 4);
    s += __shfl_xor(s, 8);  s += __shfl_xor(s, 16); s += __shfl_xor(s, 32);
    if (lane == 0) red2[half] = s;
    __syncthreads();
    if (tid == 0) {
        float m = red2[0] * (1.f / N_PTS);
        float var = red2[1] * (1.f / N_PTS) - m * m;
        float rs = rsqrtf(var + BN_EPS);
        float a = rs * g[c];
        a_out[c] = a;
        s_out[c] = b[c] - m * a;
    }
}

// ---------- BN2 stats stage 1, coalesced: bf16x8 loads, LDS transpose-reduce ----------
// grid 512 x 192 thr; block covers 32 rows in 4 passes of (8 rows x 24 thr/row).
__global__ __launch_bounds__(192) void k_stat1b(const short* __restrict__ A,
                                                float* __restrict__ part) {
    __shared__ float red[8][384];
    const int tid = threadIdx.x;
    const int g = tid / 24, m = tid % 24;
    float s8[8], q8[8];
#pragma unroll
    for (int j = 0; j < 8; ++j) { s8[j] = 0.f; q8[j] = 0.f; }
#pragma unroll
    for (int p = 0; p < 4; ++p) {
        int row = blockIdx.x * 32 + p * 8 + g;
        bf16x8 v = *(const bf16x8*)(A + row * NC + m * 8);
#pragma unroll
        for (int j = 0; j < 8; ++j) {
            float x = bf2f(v[j]);
            s8[j] += x; q8[j] = fmaf(x, x, q8[j]);
        }
    }
#pragma unroll
    for (int j = 0; j < 8; ++j) {
        red[g][m * 8 + j] = s8[j];
        red[g][192 + m * 8 + j] = q8[j];
    }
    __syncthreads();
    float S = 0.f, Q = 0.f;
#pragma unroll
    for (int gg = 0; gg < 8; ++gg) { S += red[gg][tid]; Q += red[gg][192 + tid]; }
    part[blockIdx.x * 384 + tid] = S;
    part[blockIdx.x * 384 + 192 + tid] = Q;
}

// ---------- GEMM1: T(bf16) = A @ W1; A = feat (L0) or relu(feat + bn3_L0(T2)) (L1) ----------
// 256 blocks x 256 thr; wave = 16 rows; partials -> part. X1 stored bf16.
__global__ __launch_bounds__(256) void k_gemm1(const float* __restrict__ feat,
                                               const short* __restrict__ T2prev,
                                               const float* __restrict__ st3prev,
                                               short* __restrict__ X1,
                                               const short* __restrict__ W1b,
                                               short* __restrict__ T,
                                               float* __restrict__ part) {
    __shared__ float red[4][384];
    const int tid = threadIdx.x;
    const int wave = tid >> 6, lane = tid & 63;
    const int quad = lane >> 4, cl = lane & 15;
    const int r0 = blockIdx.x * 64 + wave * 16;
    const int row = r0 + cl;

    f32x4 acc[12];
#pragma unroll
    for (int nt = 0; nt < 12; ++nt) acc[nt] = (f32x4){0.f, 0.f, 0.f, 0.f};

#pragma unroll
    for (int ks = 0; ks < 6; ++ks) {
        const int k0 = ks * 32 + quad * 8;
        const float* ap = feat + row * NC + k0;
        float4 a0 = *(const float4*)ap;
        float4 a1v = *(const float4*)(ap + 4);
        float x[8] = {a0.x, a0.y, a0.z, a0.w, a1v.x, a1v.y, a1v.z, a1v.w};
        if (T2prev) {   // fused skip: x = relu(feat + bn3_L0(T2)); store X1 (bf16)
            bf16x8 t2 = *(const bf16x8*)(T2prev + row * NC + k0);
            float4 pa0 = *(const float4*)(st3prev + k0), pa1 = *(const float4*)(st3prev + k0 + 4);
            float4 ps0 = *(const float4*)(st3prev + 192 + k0), ps1 = *(const float4*)(st3prev + 192 + k0 + 4);
            float pav[8] = {pa0.x, pa0.y, pa0.z, pa0.w, pa1.x, pa1.y, pa1.z, pa1.w};
            float psv[8] = {ps0.x, ps0.y, ps0.z, ps0.w, ps1.x, ps1.y, ps1.z, ps1.w};
#pragma unroll
            for (int j = 0; j < 8; ++j)
                x[j] = fmaxf(x[j] + fmaf(pav[j], bf2f(t2[j]), psv[j]), 0.f);
        }
        bf16x8 af;
#pragma unroll
        for (int j = 0; j < 8; ++j) af[j] = f2bf(x[j]);
        if (T2prev) *(bf16x8*)(X1 + row * NC + k0) = af;
#pragma unroll
        for (int nt = 0; nt < 12; ++nt) {
            bf16x8 bf = *(const bf16x8*)(W1b + ((nt * 6 + ks) * 64 + lane) * 8);
            acc[nt] = __builtin_amdgcn_mfma_f32_16x16x32_bf16(af, bf, acc[nt], 0, 0, 0);
        }
    }
#pragma unroll
    for (int nt = 0; nt < 12; ++nt) {
        int c = nt * 16 + cl;
        float s = 0.f, sq = 0.f;
#pragma unroll
        for (int r = 0; r < 4; ++r) {
            float v = acc[nt][r];
            T[(r0 + quad * 4 + r) * NC + c] = f2bf(v);
            s += v; sq = fmaf(v, v, sq);
        }
        s += __shfl_xor(s, 16); s += __shfl_xor(s, 32);
        sq += __shfl_xor(sq, 16); sq += __shfl_xor(sq, 32);
        if (quad == 0) { red[wave][c] = s; red[wave][192 + c] = sq; }
    }
    __syncthreads();
    for (int t = tid; t < 384; t += 256)
        part[blockIdx.x * 384 + t] = red[0][t] + red[1][t] + red[2][t] + red[3][t];
}

// ---------- kpconv: U = sum_h (infl @ Wk)[h,c] * relu(bn1(T[ref[h]]))[h,c] ----------
// grid 2048 x 512 thr (8 waves = 8 points per block). One point per wave.
// kp as float4 (|kp|^2 in .w, 1e9 sentinel pads); BN1 inline from LDS.
__global__ __launch_bounds__(512) void k_kpconv(const float* __restrict__ coord,
                                                const int* __restrict__ ridx,
                                                const float* __restrict__ kp,
                                                const short* __restrict__ Wkb,
                                                const short* __restrict__ T,
                                                const float* __restrict__ st1,
                                                short* __restrict__ U) {
    __shared__ __align__(16) short wk_s[12288];     // 24 KiB Wk B-frags
    __shared__ __align__(16) float4 kp_s[64];
    __shared__ float a1s[192], s1s[192];

    const int tid = threadIdx.x;
    {
        const float4* src = (const float4*)Wkb;
        float4* dst = (float4*)wk_s;
        for (int j = tid; j < 1536; j += 512) dst[j] = src[j];
        if (tid < 64) {
            bool ok = tid < NK;
            float x = ok ? kp[tid * 3 + 0] : 1e9f;
            float y = ok ? kp[tid * 3 + 1] : 1e9f;
            float z = ok ? kp[tid * 3 + 2] : 1e9f;
            kp_s[tid] = (float4){x, y, z, fmaf(x, x, fmaf(y, y, z * z))};
        }
        if (tid < 192) { a1s[tid] = st1[tid]; s1s[tid] = st1[192 + tid]; }
    }
    __syncthreads();

    const int wave = tid >> 6, lane = tid & 63;
    const int quad = lane >> 4, cl = lane & 15;
    const int n = blockIdx.x * 8 + wave;

    // per-point setup: lanes 0..15 load neighbor idx + relative coords, bcast via shfl
    int idh = 0; float nbx = 0.f, nby = 0.f, nbz = 0.f;
    if (lane < NH) {
        idh = ridx[n * NH + lane];
        float cx = coord[n * 3 + 0], cy = coord[n * 3 + 1], cz = coord[n * 3 + 2];
        nbx = coord[idh * 3 + 0] - cx;
        nby = coord[idh * 3 + 1] - cy;
        nbz = coord[idh * 3 + 2] - cz;
    }
    const float nx = __shfl(nbx, cl), ny = __shfl(nby, cl), nz = __shfl(nbz, cl);
    int rowb[4];
#pragma unroll
    for (int r = 0; r < 4; ++r) rowb[r] = __shfl(idh, quad * 4 + r) * NC;

    // ---- hoisted gather: all 48 loads issued before influence+MFMA compute ----
    unsigned short xv[12][4];
    const unsigned short* Tu = (const unsigned short*)T;
#pragma unroll
    for (int nt = 0; nt < 12; ++nt)
#pragma unroll
        for (int r = 0; r < 4; ++r)
            xv[nt][r] = Tu[rowb[r] + nt * 16 + cl];

    // ---- influence A-fragments: d^2 = |nb|^2 + |kp|^2 - 2 nb.kp (reference's form)
    const float nb2 = fmaf(nx, nx, fmaf(ny, ny, nz * nz));
    const float m2x = -2.f * nx, m2y = -2.f * ny, m2z = -2.f * nz;
    bf16x8 af[2];
#pragma unroll
    for (int ks = 0; ks < 2; ++ks) {
#pragma unroll
        for (int j = 0; j < 8; ++j) {
            int k = ks * 32 + quad * 8 + j;
            float4 kpv = kp_s[k];
            float t = nb2 + kpv.w;
            t = fmaf(m2x, kpv.x, t);
            t = fmaf(m2y, kpv.y, t);
            t = fmaf(m2z, kpv.z, t);
            float d = sqrtf(fmaxf(t, 0.f));
            af[ks][j] = f2bf(fmaxf(1.f - d, 0.f));   // SIGMA = 1; pads -> 0
        }
    }

    // ---- A = infl @ Wk via MFMA (12 n-tiles x 2 k-steps), B-frags from LDS
    f32x4 acc[12];
#pragma unroll
    for (int nt = 0; nt < 12; ++nt) {
        bf16x8 b0 = *(const bf16x8*)(wk_s + ((nt * 2 + 0) * 64 + lane) * 8);
        bf16x8 b1v = *(const bf16x8*)(wk_s + ((nt * 2 + 1) * 64 + lane) * 8);
        f32x4 z = (f32x4){0.f, 0.f, 0.f, 0.f};
        z = __builtin_amdgcn_mfma_f32_16x16x32_bf16(af[0], b0, z, 0, 0, 0);
        acc[nt] = __builtin_amdgcn_mfma_f32_16x16x32_bf16(af[1], b1v, z, 0, 0, 0);
    }

    // ---- aggregate: U[n,c] = sum_h acc[h,c] * relu(bn1(xv[h,c]))
#pragma unroll
    for (int nt = 0; nt < 12; ++nt) {
        const float a1c = a1s[nt * 16 + cl], s1c = s1s[nt * 16 + cl];
        float u = 0.f;
#pragma unroll
        for (int r = 0; r < 4; ++r) {
            float t = bf2f((short)xv[nt][r]);
            float x = fmaxf(fmaf(a1c, t, s1c), 0.f);
            u = fmaf(acc[nt][r], x, u);
        }
        u += __shfl_xor(u, 16);
        u += __shfl_xor(u, 32);
        if (quad == 0) U[n * NC + nt * 16 + cl] = f2bf(u);
    }
}

// ---------- GEMM3: T2(bf16) = relu(bn2(U)) @ W3; partials -> part ----------
__global__ __launch_bounds__(256) void k_gemm3(const short* __restrict__ U,
                                               const float* __restrict__ st2,
                                               const short* __restrict__ W3b,
                                               short* __restrict__ T2,
                                               float* __restrict__ part) {
    __shared__ float red[4][384];
    const int tid = threadIdx.x;
    const int wave = tid >> 6, lane = tid & 63;
    const int quad = lane >> 4, cl = lane & 15;
    const int r0 = blockIdx.x * 64 + wave * 16;
    const int row = r0 + cl;

    f32x4 acc[12];
#pragma unroll
    for (int nt = 0; nt < 12; ++nt) acc[nt] = (f32x4){0.f, 0.f, 0.f, 0.f};

#pragma unroll
    for (int ks = 0; ks < 6; ++ks) {
        const int k0 = ks * 32 + quad * 8;
        bf16x8 u8 = *(const bf16x8*)(U + row * NC + k0);
        float4 aa0 = *(const float4*)(st2 + k0), aa1 = *(const float4*)(st2 + k0 + 4);
        float4 ss0 = *(const float4*)(st2 + 192 + k0), ss1 = *(const float4*)(st2 + 192 + k0 + 4);
        float av[8] = {aa0.x, aa0.y, aa0.z, aa0.w, aa1.x, aa1.y, aa1.z, aa1.w};
        float sv[8] = {ss0.x, ss0.y, ss0.z, ss0.w, ss1.x, ss1.y, ss1.z, ss1.w};
        bf16x8 af;
#pragma unroll
        for (int j = 0; j < 8; ++j)
            af[j] = f2bf(fmaxf(fmaf(av[j], bf2f(u8[j]), sv[j]), 0.f));
#pragma unroll
        for (int nt = 0; nt < 12; ++nt) {
            bf16x8 bf = *(const bf16x8*)(W3b + ((nt * 6 + ks) * 64 + lane) * 8);
            acc[nt] = __builtin_amdgcn_mfma_f32_16x16x32_bf16(af, bf, acc[nt], 0, 0, 0);
        }
    }
#pragma unroll
    for (int nt = 0; nt < 12; ++nt) {
        int c = nt * 16 + cl;
        float s = 0.f, sq = 0.f;
#pragma unroll
        for (int r = 0; r < 4; ++r) {
            float v = acc[nt][r];
            T2[(r0 + quad * 4 + r) * NC + c] = f2bf(v);
            s += v; sq = fmaf(v, v, sq);
        }
        s += __shfl_xor(s, 16); s += __shfl_xor(s, 32);
        sq += __shfl_xor(sq, 16); sq += __shfl_xor(sq, 32);
        if (quad == 0) { red[wave][c] = s; red[wave][192 + c] = sq; }
    }
    __syncthreads();
    for (int t = tid; t < 384; t += 256)
        part[blockIdx.x * 384 + t] = red[0][t] + red[1][t] + red[2][t] + red[3][t];
}

// ---------- final: out = relu(X1 + bn3_L1(T2)), X1 bf16 ----------
__global__ __launch_bounds__(256) void k_final(const short* __restrict__ T2,
                                               const float* __restrict__ st3,
                                               const short* __restrict__ X1,
                                               float* __restrict__ out) {
    const int i = blockIdx.x * 256 + threadIdx.x;   // grid covers N*NC/8 exactly
    const int c0 = (i * 8) % 192;
    bf16x8 t2 = *(const bf16x8*)(T2 + (long)i * 8);
    bf16x8 x1 = *(const bf16x8*)(X1 + (long)i * 8);
    float4 aa0 = *(const float4*)(st3 + c0), aa1 = *(const float4*)(st3 + c0 + 4);
    float4 ss0 = *(const float4*)(st3 + 192 + c0), ss1 = *(const float4*)(st3 + 192 + c0 + 4);
    float av[8] = {aa0.x, aa0.y, aa0.z, aa0.w, aa1.x, aa1.y, aa1.z, aa1.w};
    float sv[8] = {ss0.x, ss0.y, ss0.z, ss0.w, ss1.x, ss1.y, ss1.z, ss1.w};
    float4 o0, o1;
    float o[8];
#pragma unroll
    for (int j = 0; j < 8; ++j)
        o[j] = fmaxf(bf2f(x1[j]) + fmaf(av[j], bf2f(t2[j]), sv[j]), 0.f);
    o0 = (float4){o[0], o[1], o[2], o[3]};
    o1 = (float4){o[4], o[5], o[6], o[7]};
    *(float4*)(out + (long)i * 8)     = o0;
    *(float4*)(out + (long)i * 8 + 4) = o1;
}

extern "C" void kernel_launch(void* const* d_in, const int* in_sizes, int n_in,
                              void* d_out, int out_size, void* d_ws, size_t ws_size,
                              hipStream_t stream) {
    const float* coord = (const float*)d_in[0];
    const float* feat  = (const float*)d_in[1];
    const int*   ridx  = (const int*)d_in[2];
    const float* kp    = (const float*)d_in[3];
    const float* W1    = (const float*)d_in[4];
    const float* Wk    = (const float*)d_in[5];
    const float* W3    = (const float*)d_in[6];
    const float* g1    = (const float*)d_in[7];
    const float* b1    = (const float*)d_in[8];
    const float* g2    = (const float*)d_in[9];
    const float* b2    = (const float*)d_in[10];
    const float* g3    = (const float*)d_in[11];
    const float* b3    = (const float*)d_in[12];
    float* out = (float*)d_out;

    // ws (floats): part[512*384] | stats[6*384] | shorts: X1 | T | U | T2 | Wb  ~= 26 MB
    float* part  = (float*)d_ws;
    float* stats = part + 512 * 384;
    short* X1 = (short*)(stats + 2304);
    short* T  = X1 + N_PTS * NC;
    short* U  = T + N_PTS * NC;
    short* T2 = U + N_PTS * NC;
    short* Wb = T2 + N_PTS * NC;

    k_wfrag<<<336, 64, 0, stream>>>(W1, Wk, W3, Wb);

    for (int d = 0; d < ND; ++d) {
        const short* W1b = Wb + d * 86016;
        const short* Wkb = W1b + 36864;
        const short* W3b = W1b + 49152;
        float* st1 = stats + (d * 3 + 0) * 384;
        float* st2 = stats + (d * 3 + 1) * 384;
        float* st3 = stats + (d * 3 + 2) * 384;

        k_gemm1<<<256, 256, 0, stream>>>(feat,
                                         d ? T2 : (short*)nullptr,
                                         stats + 2 * 384,    // bn3 of layer 0
                                         X1, W1b, T, part);
        k_stat2<<<192, 128, 0, stream>>>(part, 256, g1 + d * NC, b1 + d * NC, st1, st1 + 192);
        k_kpconv<<<N_PTS / 8, 512, 0, stream>>>(coord, ridx, kp, Wkb, T, st1, U);
        k_stat1b<<<512, 192, 0, stream>>>(U, part);
        k_stat2<<<192, 128, 0, stream>>>(part, 512, g2 + d * NC, b2 + d * NC, st2, st2 + 192);
        k_gemm3<<<256, 256, 0, stream>>>(U, st2, W3b, T2, part);
        k_stat2<<<192, 128, 0, stream>>>(part, 256, g3 + d * NC, b3 + d * NC, st3, st3 + 192);
    }
    k_final<<<N_PTS * NC / 8 / 256, 256, 0, stream>>>(T2, stats + 5 * 384, X1, out);
}